// Round 4
// baseline (451.516 us; speedup 1.0000x reference)
//
#include <hip/hip_runtime.h>
#include <cstdint>
#include <cstddef>

#define N_ 32
#define C_ 256
#define H_ 56
#define W_ 56
#define PWORDS 4   // 256 channels / 64 bits

typedef unsigned long long u64;

// workspace layout (bytes)
static constexpr size_t PX_ELEMS = (size_t)N_ * PWORDS * H_ * W_;     // 401408 u64
static constexpr size_t PX_BYTES = PX_ELEMS * 8;                      // 3,211,264
static constexpr size_t PWB_OFF  = PX_BYTES;
static constexpr size_t PW_ELEMS = (size_t)C_ * 9 * PWORDS;           // 9216 u64
static constexpr size_t T_OFF    = PWB_OFF + PW_ELEMS * 8;
static constexpr size_t S_OFF    = T_OFF + (size_t)C_ * 9 * 4;

// ---------------- kernel 1: pack sign bits of x ----------------
// px layout: [n][word][h][w]. One wave per (n,word,h) row; lane = w.
// Each lane privately accumulates its 64 channel-sign bits: loads are
// coalesced (56 consecutive floats per instr), no cross-lane ops needed.
__global__ __launch_bounds__(256) void pack_x_kernel(const float* __restrict__ x,
                                                     u64* __restrict__ px) {
    int wid  = blockIdx.x * 4 + (threadIdx.x >> 6);   // 0..7167 = (n,word,h)
    int lane = threadIdx.x & 63;
    int h = wid % H_;
    int t = wid / H_;
    int word = t & 3;
    int n    = t >> 2;
    int wl = lane < W_ ? lane : W_ - 1;               // clamp, no divergence
    const float* xp = x + ((size_t)(n * C_ + word * 64)) * (H_ * W_) + h * W_ + wl;
    u64 bits = 0;
#pragma unroll 16
    for (int ci = 0; ci < 64; ++ci) {
        float v = xp[(size_t)ci * (H_ * W_)];
        bits |= (u64)(v > 0.0f) << ci;
    }
    if (lane < W_)
        px[(((size_t)n * PWORDS + word) * H_ + h) * W_ + lane] = bits;
}

// ---------------- kernel 2: binarize weights ----------------
// pw layout: [o][tap][word], tap = kh*3+kw; Tg[o][tap] = 256 - 2*popc256(bits)
__global__ __launch_bounds__(256) void pack_w_kernel(const float* __restrict__ wt,
                                                     u64* __restrict__ pw,
                                                     int* __restrict__ Tg,
                                                     float* __restrict__ scaleg) {
    __shared__ double red[256];
    __shared__ u64 wb[36];
    int o = blockIdx.x, tid = threadIdx.x;
    const float* wo = wt + (size_t)o * 2304;

    double s = 0;
    for (int j = tid; j < 2304; j += 256) s += (double)wo[j];
    red[tid] = s;
    __syncthreads();
    for (int k = 128; k > 0; k >>= 1) {
        if (tid < k) red[tid] += red[tid + k];
        __syncthreads();
    }
    double mean = red[0] / 2304.0;
    __syncthreads();

    double s2 = 0;
    for (int j = tid; j < 2304; j += 256) s2 += fabs((double)wo[j] - mean);
    red[tid] = s2;
    __syncthreads();
    for (int k = 128; k > 0; k >>= 1) {
        if (tid < k) red[tid] += red[tid + k];
        __syncthreads();
    }
    float scale = (float)(red[0] / 2304.0);

    if (tid < 36) {
        int tap = tid >> 2, word = tid & 3;
        u64 bits = 0;
        for (int b = 0; b < 64; ++b) {
            int i = word * 64 + b;
            double v = (double)wo[(size_t)i * 9 + tap];
            bits |= (u64)(v > mean ? 1 : 0) << b;
        }
        wb[tid] = bits;
        pw[(size_t)o * 36 + tid] = bits;
    }
    __syncthreads();
    if (tid < 9) {
        int pc = __popcll(wb[tid * 4]) + __popcll(wb[tid * 4 + 1]) +
                 __popcll(wb[tid * 4 + 2]) + __popcll(wb[tid * 4 + 3]);
        Tg[o * 9 + tid] = 256 - 2 * pc;
    }
    if (tid == 0) scaleg[o] = scale;
}

// ---------------- kernel 3: popcount conv ----------------
// block = 512 threads (8 waves): hl = tid>>5 (16 rows), wtl = tid&31
// (28 of 32 w-tiles of 2 used). Per thread: OT=8 out-channels x WT=2 w.
// Weights: wave-uniform global loads -> s_load (no VALU/LDS cost).
// 33 KB LDS + <=64 VGPR -> 4 blocks/CU = 32 waves/CU.
#define HT 16
#define OT 8
#define WT 2
#define ROWS 18      // HT + 2 halo
#define COLSP 58     // W_ + 2 halo; [word][row][col] planes, b128-aligned

__global__ __launch_bounds__(512, 8) void conv_kernel(const u64* __restrict__ px,
                                                      const u64* __restrict__ pw,
                                                      const int* __restrict__ Tg,
                                                      const float* __restrict__ scaleg,
                                                      float* __restrict__ out) {
    __shared__ u64 xt[PWORDS * ROWS * COLSP];  // 33408 B

    int tid = threadIdx.x;
    int h0 = blockIdx.x * HT;
    int og = blockIdx.y;
    int n  = blockIdx.z;

    // stage packed x planes (zero-padded halo); contiguous c => coalesced
    for (int i = tid; i < PWORDS * ROWS * COLSP; i += 512) {
        int word = i / (ROWS * COLSP);
        int rem  = i - word * (ROWS * COLSP);
        int r = rem / COLSP;
        int c = rem - r * COLSP;
        int gh = h0 + r - 1, gw = c - 1;
        u64 v = 0;
        if ((unsigned)gh < H_ && (unsigned)gw < W_)
            v = px[(((size_t)n * PWORDS + word) * H_ + gh) * W_ + gw];
        xt[i] = v;
    }
    __syncthreads();

    int hl  = tid >> 5;                   // 0..15
    int wtl = tid & 31;                   // 0..31; only 0..27 store
    int w0  = (wtl < 28 ? wtl : 27) * WT; // even -> b128-aligned LDS reads
    int h   = h0 + hl;

    int acc[OT][WT];
#pragma unroll
    for (int o = 0; o < OT; ++o)
#pragma unroll
        for (int wi = 0; wi < WT; ++wi) acc[o][wi] = 0;

    for (int kh = 0; kh < 3; ++kh) {
        int r = hl + kh;
        for (int word = 0; word < PWORDS; ++word) {
            const u64* row = &xt[(word * ROWS + r) * COLSP + w0];
            ulonglong2 p0 = *(const ulonglong2*)(row);
            ulonglong2 p1 = *(const ulonglong2*)(row + 2);
            u64 xv0 = p0.x, xv1 = p0.y, xv2 = p1.x, xv3 = p1.y;
            // wave-uniform weight base for this (kh, word) -> s_load
            const u64* wb = pw + (size_t)(og * OT) * 36 + kh * 12 + word;
#pragma unroll
            for (int o = 0; o < OT; ++o) {
                u64 wv0 = wb[o * 36];       // kw=0
                u64 wv1 = wb[o * 36 + 4];   // kw=1
                u64 wv2 = wb[o * 36 + 8];   // kw=2
                acc[o][0] += __popcll(xv0 ^ wv0);
                acc[o][0] += __popcll(xv1 ^ wv1);
                acc[o][0] += __popcll(xv2 ^ wv2);
                acc[o][1] += __popcll(xv1 ^ wv0);
                acc[o][1] += __popcll(xv2 ^ wv1);
                acc[o][1] += __popcll(xv3 ^ wv2);
            }
        }
    }

    if (wtl >= 28 || h >= H_) return;

    // border correction: 9-bit invalid-tap masks per output column
    int inv0 = 0, inv1 = 0;
    bool border = (h == 0) | (h == H_ - 1) | (wtl == 0) | (wtl == 27);
    if (border) {
        for (int kh = 0; kh < 3; ++kh) {
            int ih = h + kh - 1;
            bool rI = (unsigned)ih >= H_;
            for (int kw = 0; kw < 3; ++kw) {
                int bit = 1 << (kh * 3 + kw);
                int iw = w0 + kw - 1;
                if (rI | ((unsigned)(iw + 0) >= W_)) inv0 |= bit;
                if (rI | ((unsigned)(iw + 1) >= W_)) inv1 |= bit;
            }
        }
    }

    size_t obase = ((size_t)(n * C_ + og * OT) * H_ + h) * W_ + w0;
#pragma unroll
    for (int o = 0; o < OT; ++o) {
        float s = scaleg[og * OT + o];
        int c0 = 0, c1 = 0;
        if (border) {
            for (int t = 0; t < 9; ++t) {
                int tv = Tg[(og * OT + o) * 9 + t];
                if ((inv0 >> t) & 1) c0 += tv;
                if ((inv1 >> t) & 1) c1 += tv;
            }
        }
        float2 v;
        v.x = s * (float)(2304 - 2 * acc[o][0] - c0);
        v.y = s * (float)(2304 - 2 * acc[o][1] - c1);
        *(float2*)(out + obase + (size_t)o * (H_ * W_)) = v;
    }
}

extern "C" void kernel_launch(void* const* d_in, const int* in_sizes, int n_in,
                              void* d_out, int out_size, void* d_ws, size_t ws_size,
                              hipStream_t stream) {
    const float* x   = (const float*)d_in[0];
    const float* wgt = (const float*)d_in[1];
    float* out = (float*)d_out;
    char* ws = (char*)d_ws;

    u64*   px = (u64*)ws;
    u64*   pw = (u64*)(ws + PWB_OFF);
    int*   Tg = (int*)(ws + T_OFF);
    float* sg = (float*)(ws + S_OFF);

    // 32*4*56 = 7168 waves / 4 per block = 1792 blocks
    pack_x_kernel<<<dim3(1792), dim3(256), 0, stream>>>(x, px);
    pack_w_kernel<<<dim3(256), dim3(256), 0, stream>>>(wgt, pw, Tg, sg);
    conv_kernel<<<dim3(4, C_ / OT, N_), dim3(512), 0, stream>>>(px, pw, Tg, sg, out);
}

// Round 5
// 274.909 us; speedup vs baseline: 1.6424x; 1.6424x over previous
//
#include <hip/hip_runtime.h>
#include <cstdint>
#include <cstddef>

#define N_ 32
#define C_ 256
#define H_ 56
#define W_ 56

typedef int v4i __attribute__((ext_vector_type(4)));

// ---- workspace layout ----
// sx: padded sign-activations, i8, [n][58 rows][68 w][256 c]
static constexpr size_t SX_BYTES = (size_t)N_ * 58 * 68 * 256;   // 32,309,248
static constexpr size_t WB_OFF   = SX_BYTES;
static constexpr size_t WB_BYTES = 36ull * 16 * 64 * 16;         // 589,824 (kiter, ogroup, lane, 16B)
static constexpr size_t SC_OFF   = WB_OFF + WB_BYTES;            // 256 floats

// ---------------- kernel 0: zero the padded sx buffer ----------------
__global__ __launch_bounds__(256) void zero_sx(v4i* __restrict__ p) {
    size_t i = (size_t)blockIdx.x * 256 + threadIdx.x;   // grid sized exactly
    v4i z = {0, 0, 0, 0};
    p[i] = z;
}

// ---------------- kernel 1: pack x signs -> NHWC i8 (padded) ----------------
// block: (hw-tile of 64, channel-block of 64, n). LDS float transpose.
__global__ __launch_bounds__(256) void pack_x(const float* __restrict__ x,
                                              char* __restrict__ sx) {
    __shared__ float tile[64 * 65];
    int tid = threadIdx.x;
    int hw0 = blockIdx.x * 64;     // 49 tiles cover 3136 exactly
    int cb0 = blockIdx.y;          // 0..3 (64 channels each)
    int n   = blockIdx.z;

    int cl = tid >> 6, hwl = tid & 63;
    const float* xb = x + ((size_t)n * C_ + cb0 * 64) * 3136 + hw0;
#pragma unroll
    for (int i = 0; i < 16; ++i) {
        int cloc = i * 4 + cl;
        tile[cloc * 65 + hwl] = xb[(size_t)cloc * 3136 + hwl];   // coalesced
    }
    __syncthreads();

    int hwl2 = tid >> 2, cq = tid & 3;
    int hw = hw0 + hwl2;
    int h = hw / 56, w = hw - h * 56;
    int words[4];
#pragma unroll
    for (int g = 0; g < 4; ++g) {
        int word = 0;
#pragma unroll
        for (int b = 0; b < 4; ++b) {
            float v = tile[(cq * 16 + g * 4 + b) * 65 + hwl2];
            int s = (v > 0.0f) - (v < 0.0f);    // exact sign, 0 at 0
            word |= (s & 0xff) << (8 * b);
        }
        words[g] = word;
    }
    v4i o4 = {words[0], words[1], words[2], words[3]};
    *(v4i*)(sx + (((size_t)n * 58 + h + 1) * 68 + (w + 1)) * 256 + cb0 * 64 + cq * 16) = o4;
}

// ---------------- kernel 2: binarize weights into MFMA B-fragment layout ----
// wB[kiter][og][lane][16B]: element j = sign(w[o= og*16 + (lane&15)]
//                                         [c = cb*64 + (lane>>4)*16 + j][kh][kw] - mean_o)
// kiter = (kh*3+kw)*4 + cb
__global__ __launch_bounds__(256) void pack_w(const float* __restrict__ wt,
                                              char* __restrict__ wB,
                                              float* __restrict__ scaleg) {
    __shared__ double red[256];
    int o = blockIdx.x, tid = threadIdx.x;
    const float* wo = wt + (size_t)o * 2304;

    double s = 0;
    for (int j = tid; j < 2304; j += 256) s += (double)wo[j];
    red[tid] = s;
    __syncthreads();
    for (int k = 128; k > 0; k >>= 1) {
        if (tid < k) red[tid] += red[tid + k];
        __syncthreads();
    }
    double mean = red[0] / 2304.0;
    __syncthreads();

    double s2 = 0;
    for (int j = tid; j < 2304; j += 256) s2 += fabs((double)wo[j] - mean);
    red[tid] = s2;
    __syncthreads();
    for (int k = 128; k > 0; k >>= 1) {
        if (tid < k) red[tid] += red[tid + k];
        __syncthreads();
    }
    if (tid == 0) scaleg[o] = (float)(red[0] / 2304.0);

    if (tid < 144) {
        int kiter = tid >> 2, q = tid & 3;     // kiter 0..35, q = k-quad
        int tap = kiter >> 2, cb = kiter & 3;
        int kh = tap / 3, kw = tap - kh * 3;
        int words[4];
        for (int g = 0; g < 4; ++g) {
            int word = 0;
            for (int b = 0; b < 4; ++b) {
                int c = cb * 64 + q * 16 + g * 4 + b;
                double v = (double)wo[c * 9 + kh * 3 + kw];
                int sg = (v > mean) - (v < mean);
                word |= (sg & 0xff) << (8 * b);
            }
            words[g] = word;
        }
        v4i pk = {words[0], words[1], words[2], words[3]};
        *(v4i*)(wB + (((size_t)kiter * 16 + (o >> 4)) * 64 + q * 16 + (o & 15)) * 16) = pk;
    }
}

// ---------------- kernel 3: i8 MFMA implicit-GEMM conv ----------------
// block = (h, n), 256 threads = 4 waves. Each wave: 4 o-frags (64 channels),
// 4 m-frags (64 w positions, 56 valid). K = 9 taps x 4 channel-blocks of 64.
// x rows staged in LDS with 16B-chunk swizzle (phys = (chunk + w) & 15).
__global__ __launch_bounds__(256, 3) void conv_mfma(const char* __restrict__ sx,
                                                    const v4i* __restrict__ wB,
                                                    const float* __restrict__ scaleg,
                                                    float* __restrict__ out) {
    __shared__ char xs[3 * 68 * 256];   // 52224 B
    int tid = threadIdx.x;
    int wave = tid >> 6, lane = tid & 63;
    int h = blockIdx.x, n = blockIdx.y;

    // stage 3 padded rows (h, h+1, h+2 of sx = input rows h-1..h+1)
    const char* src = sx + ((size_t)n * 58 + h) * (68 * 256);
    for (int i = tid; i < 3 * 68 * 16; i += 256) {
        int w = (i >> 4) % 68;
        v4i v = *(const v4i*)(src + (size_t)i * 16);
        int phys = (i & ~15) | ((i + w) & 15);   // swizzle 16B chunk within position
        *(v4i*)(xs + (size_t)phys * 16) = v;
    }
    __syncthreads();

    int lm = lane & 15, q = lane >> 4;
    v4i acc[4][4];
#pragma unroll
    for (int mf = 0; mf < 4; ++mf)
#pragma unroll
        for (int of = 0; of < 4; ++of) {
            v4i z = {0, 0, 0, 0};
            acc[mf][of] = z;
        }

    for (int dh = 0; dh < 3; ++dh)
        for (int dw = 0; dw < 3; ++dw)
            for (int cb = 0; cb < 4; ++cb) {
                int kiter = (dh * 3 + dw) * 4 + cb;
                v4i b[4];
#pragma unroll
                for (int of = 0; of < 4; ++of)
                    b[of] = wB[((size_t)kiter * 16 + wave * 4 + of) * 64 + lane];
                v4i a[4];
#pragma unroll
                for (int mf = 0; mf < 4; ++mf) {
                    int win = mf * 16 + lm + dw;          // padded w index, <= 65
                    int phys = ((dh * 68 + win) << 4) | ((cb * 4 + q + win) & 15);
                    a[mf] = *(const v4i*)(xs + (size_t)phys * 16);
                }
#pragma unroll
                for (int mf = 0; mf < 4; ++mf)
#pragma unroll
                    for (int of = 0; of < 4; ++of)
                        acc[mf][of] = __builtin_amdgcn_mfma_i32_16x16x64_i8(
                            a[mf], b[of], acc[mf][of], 0, 0, 0);
            }

    // epilogue: D[m=quad*4+reg (w), o=lane&15], scale, store float4
#pragma unroll
    for (int of = 0; of < 4; ++of) {
        int o = (wave * 4 + of) * 16 + lm;
        float s = scaleg[o];
        float* ob = out + ((size_t)(n * C_ + o) * H_ + h) * W_;
#pragma unroll
        for (int mf = 0; mf < 4; ++mf) {
            int wb = mf * 16 + q * 4;
            if (wb < W_) {
                float4 v = {s * (float)acc[mf][of].x, s * (float)acc[mf][of].y,
                            s * (float)acc[mf][of].z, s * (float)acc[mf][of].w};
                *(float4*)(ob + wb) = v;
            }
        }
    }
}

extern "C" void kernel_launch(void* const* d_in, const int* in_sizes, int n_in,
                              void* d_out, int out_size, void* d_ws, size_t ws_size,
                              hipStream_t stream) {
    const float* x   = (const float*)d_in[0];
    const float* wgt = (const float*)d_in[1];
    float* out = (float*)d_out;
    char* ws = (char*)d_ws;

    char*  sx = ws;
    char*  wb = ws + WB_OFF;
    float* sg = (float*)(ws + SC_OFF);

    // 32,309,248 / 16 = 2,019,328 int4 = 7888 blocks x 256 exactly
    zero_sx<<<dim3(7888), dim3(256), 0, stream>>>((v4i*)sx);
    pack_x<<<dim3(49, 4, N_), dim3(256), 0, stream>>>(x, sx);
    pack_w<<<dim3(256), dim3(256), 0, stream>>>(wgt, wb, sg);
    conv_mfma<<<dim3(H_, N_), dim3(256), 0, stream>>>(sx, (const v4i*)wb, sg, out);
}